// Round 7
// baseline (2633.368 us; speedup 1.0000x reference)
//
#include <hip/hip_runtime.h>

#define TT 365
#define BB 512
#define DD 16
#define HH 256
#define SS 32

typedef __attribute__((ext_vector_type(8))) short short8;
typedef __attribute__((ext_vector_type(4))) float f32x4;
typedef __attribute__((ext_vector_type(4))) unsigned u32x4;
typedef unsigned long long u64;

// Ring poison: tag bits (14,30) set in both dwords = tag-code 3; every region's
// first poll wants code 0 (or is written with 0..2 first) => never false-match.
#define SENT 0x7FC07FC07FC07FC0ULL
// 2-bit generation tag per dword: bit14 (low bf16) + bit30 (high bf16).
// |h|<=1 => biased exp <= 127 => both bits are 0 in any published bf16.
#define TMASK64 0x4000400040004000ULL

__device__ __host__ inline short f2bf(float f){
  union { float f; unsigned u; } v; v.f = f;
  unsigned r = v.u + 0x7FFFu + ((v.u >> 16) & 1u);
  return (short)(r >> 16);
}
__device__ inline float sigm(float x){ return 1.0f/(1.0f+__expf(-x)); }
__device__ inline float tanhx(float x){ return 2.0f/(1.0f+__expf(-2.0f*x)) - 1.0f; }

// RNE f32x2 -> packed bf16x2 (same rounding as f2bf; h is never NaN)
__device__ inline unsigned cvtpk(float a, float b){
  unsigned r;
  asm("v_cvt_pk_bf16_f32 %0, %1, %2" : "=v"(r) : "v"(a), "v"(b));
  return r;
}

// A-fragment address (shorts) in an 8KB K=256 region for mfma_16x16x32 A-layout.
__device__ inline int fragAddr(int k, int m){
  return ((k>>5)*512) + ((((k&31)>>3)*16 + m)*8) + (k&7);
}

// Coherence-point store (HW-verified visible to sc0+sc1 polls in R2/R3/R5/R6).
__device__ inline void pub_store(u64* p, u64 v){
  asm volatile("global_store_dwordx2 %0, %1, off sc0 sc1"
               :: "v"(p), "v"(v) : "memory");
}

// Raw barrier: LDS-drain only; publish stores / polls / atomics stay in flight.
#define RAW_BAR() do{ \
    asm volatile("s_waitcnt lgkmcnt(0)\n\ts_barrier" ::: "memory"); \
    __builtin_amdgcn_sched_barrier(0); }while(0)

// Issue 6 dense 16B tagged-poll loads (wave0 only; 1KB/instr coalesced).
#define ISSUE6(o0,o1,o2,o3,o4,o5,a0,a1,a2,a3,a4,a5) \
  asm volatile( \
    "global_load_dwordx4 %0, %6, off sc0 sc1\n\t" \
    "global_load_dwordx4 %1, %7, off sc0 sc1\n\t" \
    "global_load_dwordx4 %2, %8, off sc0 sc1\n\t" \
    "global_load_dwordx4 %3, %9, off sc0 sc1\n\t" \
    "global_load_dwordx4 %4, %10, off sc0 sc1\n\t" \
    "global_load_dwordx4 %5, %11, off sc0 sc1" \
    : "=&v"(o0),"=&v"(o1),"=&v"(o2),"=&v"(o3),"=&v"(o4),"=&v"(o5) \
    : "v"(a0),"v"(a1),"v"(a2),"v"(a3),"v"(a4),"v"(a5) : "memory")

__device__ inline bool tok(u32x4 v, u64 tg){
  u64 lo = (((u64)v.y)<<32)|v.x, hi = (((u64)v.w)<<32)|v.z;
  return ((lo & TMASK64) == tg) && ((hi & TMASK64) == tg);
}

// Scatter one 16B poll vector (2 u64 = 2 quads of one k) into frag layout.
__device__ inline void wrx4(short* arr, int cP, int j, int lane, u32x4 v){
  int k  = cP*64 + j*32 + (lane>>1);
  int q0 = (lane&1)*2;
  u64 lo = ((((u64)v.y)<<32)|v.x) & ~TMASK64;
  u64 hi = ((((u64)v.w)<<32)|v.z) & ~TMASK64;
#pragma unroll
  for (int r=0;r<4;++r) arr[fragAddr(k, q0*4+r)]     = (short)(lo>>(16*r));
#pragma unroll
  for (int r=0;r<4;++r) arr[fragAddr(k, (q0+1)*4+r)] = (short)(hi>>(16*r));
}

// ---------------- prep kernels ----------------
__global__ void prep_weights(const float* __restrict__ Wih0, const float* __restrict__ Whh0,
                             const float* __restrict__ Wih1, const float* __restrict__ Whh1,
                             short* __restrict__ Wb0, short* __restrict__ Wb1)
{
  int idx = blockIdx.x*blockDim.x + threadIdx.x;
  const int n0 = 16*36*512;
  const int n1 = 16*64*512;
  if (idx < n0){
    int frag = idx >> 9, pos = idx & 511;
    int lane = pos >> 3, jj = pos & 7;
    int slot = frag / 36, rem = frag % 36;
    int ks = rem >> 2, nt = rem & 3;
    int n = nt*256 + slot*16 + (lane & 15);
    float v = 0.0f;
    if (ks == 0){
      int k32 = (lane>>4)*8 + jj;
      if (k32 < 16) v = Wih0[n*16 + k32];
    } else {
      int k = (ks-1)*32 + (lane>>4)*8 + jj;
      v = Whh0[n*256 + k];
    }
    Wb0[idx] = f2bf(v);
  } else if (idx < n0 + n1){
    int e = idx - n0;
    int frag = e >> 9, pos = e & 511;
    int lane = pos >> 3, jj = pos & 7;
    int slot = frag >> 6, rem = frag & 63;
    int ks = rem >> 2, nt = rem & 3;
    int n = nt*256 + slot*16 + (lane & 15);
    int k = ks*32 + (lane>>4)*8 + jj;
    float v = (k < 256) ? Wih1[n*256 + k] : Whh1[n*256 + (k-256)];
    Wb1[e] = f2bf(v);
  }
}

__global__ void prep_h0(const float* __restrict__ xs, const float* __restrict__ Ws,
                        const float* __restrict__ bs, float* __restrict__ h0init)
{
  int i = blockIdx.x*blockDim.x + threadIdx.x;
  int b = i >> 8, jj = i & 255;
  float s = bs[jj];
  const float* xr = xs + b*SS;
  const float* wr = Ws + jj*SS;
#pragma unroll
  for (int q=0;q<SS;++q) s += xr[q]*wr[q];
  h0init[i] = s;
}

__global__ void prep_bias(const float* __restrict__ a0, const float* __restrict__ a1,
                          const float* __restrict__ a2, const float* __restrict__ a3,
                          float* __restrict__ b0o, float* __restrict__ b1o)
{
  int i = threadIdx.x + blockIdx.x*blockDim.x;
  if (i < 1024) b0o[i] = a0[i] + a1[i];
  else if (i < 2048) b1o[i-1024] = a2[i-1024] + a3[i-1024];
}

__global__ void prep_zero(float* __restrict__ out, u64* __restrict__ ring)
{
  int i = blockIdx.x*blockDim.x + threadIdx.x;
  if (i < BB*TT) out[i] = 0.0f;
  if (i < 131072) ring[i] = SENT;   // 2 slots x 32 g x (1024 h0 + 1024 h1) u64 = 1MB
}

// ---------------- persistent fused LSTM ----------------
// 128 blocks x 256 threads; g = bid&31 (16 batch rows), c = bid>>5 (64 hidden cols).
// Weights register/AGPR-resident. Lag pipeline: superstep s runs L0@t=s, L1@t=s-1.
//
// Ring region per (slot,g): [h0: 1024 u64][h1: 1024 u64] — SPLIT layout so every
// publish (64 u64/wave) and poll (128 u64/instr) is a dense contiguous burst.
// Tagged packets: slot s&1, 2-bit tag T=(s>>1)&3 in (bit14,bit30) of every dword
// (Delta-s=8 to collide; mutual consumption bounds skew<=1 => no ABA).
//
// Roles: wave0 = poller (6x dwordx4 per phase, consumes into LDS frags);
// wave1 (tids 64-79) = out-flusher (atomic never enters wave0's vmcnt stream);
// ALL loop VMEM is inline asm => zero compiler-inserted vmcnt drains.
// Counted waits (wave0 stream: [h1polls x6, xf, pubH0, h0polls x6, pubH1]):
//   h1-check vmcnt(2) (leaves xf+pubH0), h0-check vmcnt(1) (leaves pubH1).
// Waves1-3 ([{atomic}, xf, pubH0, pubH1]): vmcnt(2) before AX (leaves pubs).
__global__ __launch_bounds__(256, 1) void lstm_fused(
    const short* __restrict__ Wb0, const short* __restrict__ Wb1,
    const float* __restrict__ h0i, const float* __restrict__ b0c,
    const float* __restrict__ b1c, const float* __restrict__ x,
    const float* __restrict__ Wo, const float* __restrict__ bo,
    u64* __restrict__ ring, float* __restrict__ out)
{
  __shared__ alignas(16) short AX[2][512];
  __shared__ alignas(16) short AH0[2][4096];
  __shared__ alignas(16) short AH1[4096];
  __shared__ float outacc[2][16][4];

  const int tid  = threadIdx.x;
  const int w    = tid >> 6;
  const int lane = tid & 63;
  const int col16= lane & 15;
  const int quad = lane >> 4;
  const int c    = blockIdx.x >> 5;
  const int g    = blockIdx.x & 31;
  const int rowbase = g * 16;
  const int slot = c*4 + w;
  const int colg = slot*16 + col16;
  const bool w0  = (w == 0);

  // ---- register-resident weight fragments ----
  short8 F0[36], F1[64];
  {
    const short8* p0 = (const short8*)Wb0 + slot*36*64 + lane;
#pragma unroll
    for (int f=0; f<36; ++f) F0[f] = p0[f*64];
    const short8* p1 = (const short8*)Wb1 + slot*64*64 + lane;
#pragma unroll
    for (int f=0; f<64; ++f) F1[f] = p1[f*64];
  }
  float bia0[4], bia1[4];
#pragma unroll
  for (int nt=0; nt<4; ++nt){
    bia0[nt] = b0c[nt*256 + slot*16 + col16];
    bia1[nt] = b1c[nt*256 + slot*16 + col16];
  }
  const float wo = Wo[colg];
  const float bos = bo[0];

  // ---- init ----
  float c0[4], c1[4];
#pragma unroll
  for (int r=0; r<4; ++r){
    c0[r] = h0i[(rowbase + quad*4 + r)*HH + colg];
    c1[r] = c0[r];
  }
  for (int i = tid; i < 4096; i += 256){
    int m = i >> 8, k = i & 255;
    short v = f2bf(h0i[(rowbase+m)*HH + k]);
    int a = fragAddr(k,m);
    AH0[0][a] = v;        // h0(-1) = h0init
    AH1[a]    = v;        // h1(-1) = h0init (used at s==1)
  }
  {
    int m = tid >> 4, d = tid & 15;
    AX[0][fragAddr(d, m)] = f2bf(x[(rowbase+m)*TT*DD + d]);
    AX[0][fragAddr(16 + d, m)] = 0;
    AX[1][fragAddr(16 + d, m)] = 0;
  }
  __syncthreads();

  const f32x4 zero = {0.0f,0.0f,0.0f,0.0f};
  const int ca = (c+1)&3, cb = (c+2)&3, cc2 = (c+3)&3;

  u64 pv1_prev = 0;   // my h1(s-2) packed, carried across the step boundary

  for (int s=0; s<=TT; ++s){
    const bool doL0 = (s < TT);
    const bool doL1 = (s >= 1);
    const bool doH1x = (s >= 2);
    const int  p = s & 1;
    const unsigned T0 = (s>>1)&3;
    const unsigned w32_0 = ((T0&1)?0x4000u:0u) | ((T0&2)?0x40000000u:0u);
    const u64 tg0 = ((u64)w32_0<<32)|w32_0;
    const unsigned T1 = ((s-1)>>1)&3;
    const unsigned w32_1 = ((T1&1)?0x4000u:0u) | ((T1&2)?0x40000000u:0u);
    const u64 tg1 = ((u64)w32_1<<32)|w32_1;

    short* ax   = AX[p];   short* ah0   = AH0[p];
    short* ax_n = AX[p^1]; short* ah0_n = AH0[p^1];
    u64* const rgn0 = ring + (u64)(p*32+g)*2048;          // this step: h0 @0, h1 @1024
    u64* const rgn1 = ring + (u64)(((s-1)&1)*32+g)*2048;  // prev step (h1 polls)

    // wave0 poll addresses (dense: 2 x 1KB per partner slice)
    const u64* A0 = rgn1 + 1024 + ca *256 + lane*2;  const u64* A1 = A0 + 128;
    const u64* B0p= rgn1 + 1024 + cb *256 + lane*2;  const u64* B1p= B0p + 128;
    const u64* C0p= rgn1 + 1024 + cc2*256 + lane*2;  const u64* C1p= C0p + 128;
    const u64* D0 = rgn0 + ca *256 + lane*2;         const u64* D1 = D0 + 128;
    const u64* E0 = rgn0 + cb *256 + lane*2;         const u64* E1 = E0 + 128;
    const u64* G0 = rgn0 + cc2*256 + lane*2;         const u64* G1 = G0 + 128;

    RAW_BAR();  // B0

    // wave1: flush out(t=s-2) — atomic lives outside wave0's vmcnt stream
    if (doH1x && tid >= 64 && tid < 80){
      int row = tid - 64;
      float v = outacc[p^1][row][0] + outacc[p^1][row][1]
              + outacc[p^1][row][2] + outacc[p^1][row][3];
      if (c == 0) v += bos;
      atomicAdd(&out[(rowbase + row)*TT + (s-2)], v);
    }

    // wave0: issue h1(s-2) polls (one-step-old data: round-0 hit)
    u32x4 ya0,ya1,yb0,yb1,yc0,yc1;
    if (w0 && doH1x){ ISSUE6(ya0,ya1,yb0,yb1,yc0,yc1, A0,A1,B0p,B1p,C0p,C1p); }

    // all: x prefetch via asm (kept out of compiler's waitcnt model)
    float xf = 0.0f;
    if (s+1 < TT){
      const float* xp = x + (rowbase+(tid>>4))*TT*DD + (s+1)*DD + (tid&15);
      asm volatile("global_load_dword %0, %1, off" : "=&v"(xf) : "v"(xp) : "memory");
    }

    // ---- L0: 36 MFMA -> epi -> publish h0(s) -> own h0 frags ----
    u64 pv0 = 0;
    if (doL0){
      f32x4 acc0[4];
#pragma unroll
      for (int nt=0; nt<4; ++nt) acc0[nt] = zero;
      {
        short8 a = *(const short8*)(ax + lane*8);
#pragma unroll
        for (int nt=0; nt<4; ++nt)
          acc0[nt] = __builtin_amdgcn_mfma_f32_16x16x32_bf16(a, F0[nt], acc0[nt], 0,0,0);
      }
#pragma unroll
      for (int ks=0; ks<8; ++ks){
        short8 a = *(const short8*)(ah0 + ks*512 + lane*8);
#pragma unroll
        for (int nt=0; nt<4; ++nt)
          acc0[nt] = __builtin_amdgcn_mfma_f32_16x16x32_bf16(a, F0[(ks+1)*4+nt], acc0[nt], 0,0,0);
      }
      float h0v[4];
#pragma unroll
      for (int r=0; r<4; ++r){
        float iv = sigm (acc0[0][r] + bia0[0]);
        float fv = sigm (acc0[1][r] + bia0[1]);
        float gv = tanhx(acc0[2][r] + bia0[2]);
        float ov = sigm (acc0[3][r] + bia0[3]);
        float cc = fv*c0[r] + iv*gv;
        c0[r] = cc;
        h0v[r] = ov * tanhx(cc);
      }
      pv0 = (((u64)cvtpk(h0v[2], h0v[3])) << 32) | cvtpk(h0v[0], h0v[1]);
      pub_store(rgn0 + colg*4 + quad, pv0 | tg0);   // dense 512B/wave burst
#pragma unroll
      for (int r=0; r<4; ++r)
        ah0_n[fragAddr(colg, quad*4 + r)] = (short)(pv0 >> (16*r));
    }

    // ---- L1a: Wih1 x h0(s-1) (AH0[p]) ----
    f32x4 acc1[4];
#pragma unroll
    for (int nt=0; nt<4; ++nt) acc1[nt] = zero;
    if (doL1){
#pragma unroll
      for (int ks=0; ks<8; ++ks){
        short8 a = *(const short8*)(ah0 + ks*512 + lane*8);
#pragma unroll
        for (int nt=0; nt<4; ++nt)
          acc1[nt] = __builtin_amdgcn_mfma_f32_16x16x32_bf16(a, F1[ks*4+nt], acc1[nt], 0,0,0);
      }
    }

    // ---- wave0: check h1 polls, scatter partner frags into AH1 ----
    if (w0 && doH1x){
      __builtin_amdgcn_sched_barrier(0);
      if (doL0) asm volatile("s_waitcnt vmcnt(2)" ::: "memory");  // leaves xf+pubH0
      else      asm volatile("s_waitcnt vmcnt(0)" ::: "memory");
      __builtin_amdgcn_sched_barrier(0);
      while (!(tok(ya0,tg1)&&tok(ya1,tg1)&&tok(yb0,tg1)&&
               tok(yb1,tg1)&&tok(yc0,tg1)&&tok(yc1,tg1))){
        ISSUE6(ya0,ya1,yb0,yb1,yc0,yc1, A0,A1,B0p,B1p,C0p,C1p);
        asm volatile("s_waitcnt vmcnt(0)" ::: "memory");
        __builtin_amdgcn_sched_barrier(0);
      }
      wrx4(AH1, ca, 0, lane, ya0);  wrx4(AH1, ca, 1, lane, ya1);
      wrx4(AH1, cb, 0, lane, yb0);  wrx4(AH1, cb, 1, lane, yb1);
      wrx4(AH1, cc2,0, lane, yc0);  wrx4(AH1, cc2,1, lane, yc1);
    }
    // all: own h1(s-2) frags from register
    if (doH1x){
#pragma unroll
      for (int r=0; r<4; ++r)
        AH1[fragAddr(colg, quad*4 + r)] = (short)(pv1_prev >> (16*r));
    }

    // wave0: issue h0(s) polls (partner stores landed ~L0-end; return hides under L1b)
    u32x4 za0,za1,zb0,zb1,zc0,zc1;
    if (w0 && doL0){ ISSUE6(za0,za1,zb0,zb1,zc0,zc1, D0,D1,E0,E1,G0,G1); }

    RAW_BAR();  // B1: AH1 ready (polls/stores stay in flight)

    // ---- L1b: Whh1 x h1(s-2) (AH1) -> epi -> publish h1(s-1) -> reduce ----
    u64 pv1 = 0;
    if (doL1){
#pragma unroll
      for (int ks=0; ks<8; ++ks){
        short8 a = *(const short8*)(AH1 + ks*512 + lane*8);
#pragma unroll
        for (int nt=0; nt<4; ++nt)
          acc1[nt] = __builtin_amdgcn_mfma_f32_16x16x32_bf16(a, F1[32+ks*4+nt], acc1[nt], 0,0,0);
      }
      float pr[4], h1v[4];
#pragma unroll
      for (int r=0; r<4; ++r){
        float iv = sigm (acc1[0][r] + bia1[0]);
        float fv = sigm (acc1[1][r] + bia1[1]);
        float gv = tanhx(acc1[2][r] + bia1[2]);
        float ov = sigm (acc1[3][r] + bia1[3]);
        float cc = fv*c1[r] + iv*gv;
        c1[r] = cc;
        float h = ov * tanhx(cc);
        h1v[r] = h;
        pr[r] = h * wo;
      }
      pv1 = (((u64)cvtpk(h1v[2], h1v[3])) << 32) | cvtpk(h1v[0], h1v[1]);
      if (doL0)
        pub_store(rgn0 + 1024 + colg*4 + quad, pv1 | tg0);
#pragma unroll
      for (int m=1; m<16; m<<=1){
#pragma unroll
        for (int r=0; r<4; ++r) pr[r] += __shfl_xor(pr[r], m, 64);
      }
      if (col16 == 0){
#pragma unroll
        for (int r=0; r<4; ++r) outacc[p][quad*4 + r][w] = pr[r];
      }
    }

    // ---- tail: wave0 checks h0 polls -> partner frags; all stage AX ----
    if (w0 && doL0){
      __builtin_amdgcn_sched_barrier(0);
      if (doL1) asm volatile("s_waitcnt vmcnt(1)" ::: "memory");  // leaves pubH1
      else      asm volatile("s_waitcnt vmcnt(0)" ::: "memory");
      __builtin_amdgcn_sched_barrier(0);
      while (!(tok(za0,tg0)&&tok(za1,tg0)&&tok(zb0,tg0)&&
               tok(zb1,tg0)&&tok(zc0,tg0)&&tok(zc1,tg0))){
        ISSUE6(za0,za1,zb0,zb1,zc0,zc1, D0,D1,E0,E1,G0,G1);
        asm volatile("s_waitcnt vmcnt(0)" ::: "memory");
        __builtin_amdgcn_sched_barrier(0);
      }
      wrx4(ah0_n, ca, 0, lane, za0);  wrx4(ah0_n, ca, 1, lane, za1);
      wrx4(ah0_n, cb, 0, lane, zb0);  wrx4(ah0_n, cb, 1, lane, zb1);
      wrx4(ah0_n, cc2,0, lane, zc0);  wrx4(ah0_n, cc2,1, lane, zc1);
    }
    if (s+1 < TT){
      if (!w0){
        if (s == 0) asm volatile("s_waitcnt vmcnt(1)" ::: "memory");  // [xf,pubH0]
        else        asm volatile("s_waitcnt vmcnt(2)" ::: "memory");  // [..,xf,pubH0,pubH1]
        __builtin_amdgcn_sched_barrier(0);
      }
      ax_n[fragAddr(tid & 15, tid >> 4)] = f2bf(xf);
    }

    pv1_prev = pv1;
  }

  // ---- final flush: t = TT-1 lives in outacc[TT&1] ----
  RAW_BAR();
  if (tid >= 64 && tid < 80){
    int row = tid - 64;
    const int pf = TT & 1;
    float v = outacc[pf][row][0] + outacc[pf][row][1]
            + outacc[pf][row][2] + outacc[pf][row][3];
    if (c == 0) v += bos;
    atomicAdd(&out[(rowbase + row)*TT + (TT-1)], v);
  }
}

// ---------------- launch ----------------
extern "C" void kernel_launch(void* const* d_in, const int* in_sizes, int n_in,
                              void* d_out, int out_size, void* d_ws, size_t ws_size,
                              hipStream_t stream)
{
  const float* x    = (const float*)d_in[0];
  const float* xs   = (const float*)d_in[1];
  const float* Wih0 = (const float*)d_in[2];
  const float* Whh0 = (const float*)d_in[3];
  const float* bih0 = (const float*)d_in[4];
  const float* bhh0 = (const float*)d_in[5];
  const float* Wih1 = (const float*)d_in[6];
  const float* Whh1 = (const float*)d_in[7];
  const float* bih1 = (const float*)d_in[8];
  const float* bhh1 = (const float*)d_in[9];
  const float* Ws   = (const float*)d_in[10];
  const float* bs   = (const float*)d_in[11];
  const float* Wo   = (const float*)d_in[12];
  const float* bo   = (const float*)d_in[13];
  float* out = (float*)d_out;

  char* ws = (char*)d_ws;
  short*    Wb0   = (short*)(ws);                // 589824
  short*    Wb1   = (short*)(ws + 589824);       // 1048576 -> 1638400
  float*    h0i   = (float*)(ws + 1638400);      // 524288  -> 2162688
  float*    b0cp  = (float*)(ws + 2162688);      // 4096    -> 2166784
  float*    b1cp  = (float*)(ws + 2166784);      // 4096    -> 2170880
  u64*      ring  = (u64*)(ws + 2170880);        // 1048576 -> 3219456 (~3.22 MB)

  int nswz = 16*36*512 + 16*64*512;
  hipLaunchKernelGGL(prep_weights, dim3((nswz+255)/256), dim3(256), 0, stream,
                     Wih0, Whh0, Wih1, Whh1, Wb0, Wb1);
  hipLaunchKernelGGL(prep_h0, dim3(512), dim3(256), 0, stream, xs, Ws, bs, h0i);
  hipLaunchKernelGGL(prep_bias, dim3(8), dim3(256), 0, stream, bih0, bhh0, bih1, bhh1, b0cp, b1cp);
  hipLaunchKernelGGL(prep_zero, dim3(1024), dim3(256), 0, stream, out, ring);

  hipLaunchKernelGGL(lstm_fused, dim3(128), dim3(256), 0, stream,
                     Wb0, Wb1, h0i, b0cp, b1cp, x, Wo, bo, ring, out);
}

// Round 8
// 1508.092 us; speedup vs baseline: 1.7462x; 1.7462x over previous
//
#include <hip/hip_runtime.h>

#define TT 365
#define BB 512
#define DD 16
#define HH 256
#define SS 32

typedef __attribute__((ext_vector_type(8))) short short8;
typedef __attribute__((ext_vector_type(4))) float f32x4;
typedef unsigned long long u64;

// Ring poison: tag bits (14,30) set in both dwords = tag-code 3.
#define SENT 0x7FC07FC07FC07FC0ULL
// 2-bit generation tag per dword: bit14 (low bf16) + bit30 (high bf16).
// |h|<=1 => biased exp <= 127 => both bits are 0 in any published bf16.
#define TMASK64 0x4000400040004000ULL

__device__ __host__ inline short f2bf(float f){
  union { float f; unsigned u; } v; v.f = f;
  unsigned r = v.u + 0x7FFFu + ((v.u >> 16) & 1u);
  return (short)(r >> 16);
}
__device__ inline float sigm(float x){ return 1.0f/(1.0f+__expf(-x)); }
__device__ inline float tanhx(float x){ return 2.0f/(1.0f+__expf(-2.0f*x)) - 1.0f; }

// RNE f32x2 -> packed bf16x2 (same rounding as f2bf; h is never NaN)
__device__ inline unsigned cvtpk(float a, float b){
  unsigned r;
  asm("v_cvt_pk_bf16_f32 %0, %1, %2" : "=v"(r) : "v"(a), "v"(b));
  return r;
}

// A-fragment address (shorts) in an 8KB K=256 region for mfma_16x16x32 A-layout.
__device__ inline int fragAddr(int k, int m){
  return ((k>>5)*512) + ((((k&31)>>3)*16 + m)*8) + (k&7);
}

// Coherence-point store (HW-verified visible to sc0+sc1 polls in R2/R3/R5/R6).
__device__ inline void pub_store(u64* p, u64 v){
  asm volatile("global_store_dwordx2 %0, %1, off sc0 sc1"
               :: "v"(p), "v"(v) : "memory");
}

// Raw barrier: LDS-drain only; publish stores / polls / atomics stay in flight.
#define RAW_BAR() do{ \
    asm volatile("s_waitcnt lgkmcnt(0)\n\ts_barrier" ::: "memory"); \
    __builtin_amdgcn_sched_barrier(0); }while(0)

// ---------------- prep kernels ----------------
__global__ void prep_weights(const float* __restrict__ Wih0, const float* __restrict__ Whh0,
                             const float* __restrict__ Wih1, const float* __restrict__ Whh1,
                             short* __restrict__ Wb0, short* __restrict__ Wb1)
{
  int idx = blockIdx.x*blockDim.x + threadIdx.x;
  const int n0 = 16*36*512;
  const int n1 = 16*64*512;
  if (idx < n0){
    int frag = idx >> 9, pos = idx & 511;
    int lane = pos >> 3, jj = pos & 7;
    int slot = frag / 36, rem = frag % 36;
    int ks = rem >> 2, nt = rem & 3;
    int n = nt*256 + slot*16 + (lane & 15);
    float v = 0.0f;
    if (ks == 0){
      int k32 = (lane>>4)*8 + jj;
      if (k32 < 16) v = Wih0[n*16 + k32];
    } else {
      int k = (ks-1)*32 + (lane>>4)*8 + jj;
      v = Whh0[n*256 + k];
    }
    Wb0[idx] = f2bf(v);
  } else if (idx < n0 + n1){
    int e = idx - n0;
    int frag = e >> 9, pos = e & 511;
    int lane = pos >> 3, jj = pos & 7;
    int slot = frag >> 6, rem = frag & 63;
    int ks = rem >> 2, nt = rem & 3;
    int n = nt*256 + slot*16 + (lane & 15);
    int k = ks*32 + (lane>>4)*8 + jj;
    float v = (k < 256) ? Wih1[n*256 + k] : Whh1[n*256 + (k-256)];
    Wb1[e] = f2bf(v);
  }
}

__global__ void prep_h0(const float* __restrict__ xs, const float* __restrict__ Ws,
                        const float* __restrict__ bs, float* __restrict__ h0init)
{
  int i = blockIdx.x*blockDim.x + threadIdx.x;
  int b = i >> 8, jj = i & 255;
  float s = bs[jj];
  const float* xr = xs + b*SS;
  const float* wr = Ws + jj*SS;
#pragma unroll
  for (int q=0;q<SS;++q) s += xr[q]*wr[q];
  h0init[i] = s;
}

__global__ void prep_bias(const float* __restrict__ a0, const float* __restrict__ a1,
                          const float* __restrict__ a2, const float* __restrict__ a3,
                          float* __restrict__ b0o, float* __restrict__ b1o)
{
  int i = threadIdx.x + blockIdx.x*blockDim.x;
  if (i < 1024) b0o[i] = a0[i] + a1[i];
  else if (i < 2048) b1o[i-1024] = a2[i-1024] + a3[i-1024];
}

__global__ void prep_zero(float* __restrict__ out, u64* __restrict__ ring)
{
  int i = blockIdx.x*blockDim.x + threadIdx.x;
  if (i < BB*TT) out[i] = 0.0f;
  if (i < 131072) ring[i] = SENT;   // 2 slots x 32 g x 2048 u64 = 1MB
}

// ---------------- persistent fused LSTM ----------------
// 128 blocks x 256 threads; g = bid&31 (16 batch rows), c = bid>>5 (64 hidden cols).
// Weights register/AGPR-resident. Lag pipeline: superstep s runs L0@t=s, L1@t=s-1.
//
// Exchange: generation-tagged packets {h0(s), h1(s-1)}, slot s&1, 2-BIT tag
// T=(s>>1)&3 in (bit14,bit30) of every dword (Delta-s=8 to collide; skew<=1 via
// mutual consumption => no ABA). Read-only sc0+sc1 polls; no atomics in exchange.
//
// Window-maximized schedule (R8): per superstep s, phase fractions of period P:
//  B0(0) | w1: out-flush atomic | issue h1(s-2) polls | xf asm load
//  L0 (0->0.25): 36 MFMA -> epi -> pub h0(s) -> own h0 frags
//  L1a half-1 (4 ks) ... ISSUE h0(s) polls @~0.37 (1.2kcy after pub: skew margin,
//      0.43P check window) ... L1a half-2
//  h1-check vmcnt(5) -> fill AH1 (partners + own pv1_prev)
//  B1 | L1b: 32 MFMA -> epi -> pub h1(s-1) -> reduce -> outacc[p]
//  tail: vmcnt(4) -> AX stage -> vmcnt(1) -> h0-check -> partner h0 frags
// ALL loop VMEM is inline asm => no compiler-inserted vmcnt drains.
// Stream (s>=2): [atomic(w1), h1p x3, xf, pubH0, h0p x3, pubH1].
__global__ __launch_bounds__(256, 1) void lstm_fused(
    const short* __restrict__ Wb0, const short* __restrict__ Wb1,
    const float* __restrict__ h0i, const float* __restrict__ b0c,
    const float* __restrict__ b1c, const float* __restrict__ x,
    const float* __restrict__ Wo, const float* __restrict__ bo,
    u64* __restrict__ ring, float* __restrict__ out)
{
  __shared__ alignas(16) short AX[2][512];
  __shared__ alignas(16) short AH0[2][4096];
  __shared__ alignas(16) short AH1[4096];
  __shared__ float outacc[2][16][4];

  const int tid  = threadIdx.x;
  const int w    = tid >> 6;
  const int lane = tid & 63;
  const int col16= lane & 15;
  const int quad = lane >> 4;
  const int c    = blockIdx.x >> 5;
  const int g    = blockIdx.x & 31;
  const int rowbase = g * 16;
  const int slot = c*4 + w;
  const int colg = slot*16 + col16;

  // ---- register-resident weight fragments ----
  short8 F0[36], F1[64];
  {
    const short8* p0 = (const short8*)Wb0 + slot*36*64 + lane;
#pragma unroll
    for (int f=0; f<36; ++f) F0[f] = p0[f*64];
    const short8* p1 = (const short8*)Wb1 + slot*64*64 + lane;
#pragma unroll
    for (int f=0; f<64; ++f) F1[f] = p1[f*64];
  }
  float bia0[4], bia1[4];
#pragma unroll
  for (int nt=0; nt<4; ++nt){
    bia0[nt] = b0c[nt*256 + slot*16 + col16];
    bia1[nt] = b1c[nt*256 + slot*16 + col16];
  }
  const float wo = Wo[colg];
  const float bos = bo[0];

  // ---- init ----
  float c0[4], c1[4];
#pragma unroll
  for (int r=0; r<4; ++r){
    c0[r] = h0i[(rowbase + quad*4 + r)*HH + colg];
    c1[r] = c0[r];
  }
  for (int i = tid; i < 4096; i += 256){
    int m = i >> 8, k = i & 255;
    short v = f2bf(h0i[(rowbase+m)*HH + k]);
    int a = fragAddr(k,m);
    AH0[0][a] = v;        // h0(-1) = h0init
    AH1[a]    = v;        // h1(-1) = h0init (used at s==1)
  }
  {
    int m = tid >> 4, d = tid & 15;
    AX[0][fragAddr(d, m)] = f2bf(x[(rowbase+m)*TT*DD + d]);
    AX[0][fragAddr(16 + d, m)] = 0;
    AX[1][fragAddr(16 + d, m)] = 0;
  }
  __syncthreads();

  const f32x4 zero = {0.0f,0.0f,0.0f,0.0f};
  const int qd = tid & 3;
  const int cl = (tid >> 2) & 63;
  const int ka = (((c + 1) & 3) << 6) + cl;
  const int kb = (((c + 2) & 3) << 6) + cl;
  const int kc = (((c + 3) & 3) << 6) + cl;

  u64 pv1_prev = 0;   // my h1(s-2) packed, carried across the step boundary

#define CHKW(tv,dst,fl,TG) do{ u64 _t=(tv); \
    if(!(fl) && ((_t & TMASK64)==(TG))){ (dst)=_t & ~TMASK64; (fl)=true; } }while(0)

  for (int s=0; s<=TT; ++s){
    const bool doL0 = (s < TT);
    const bool doL1 = (s >= 1);
    const bool doH1x = (s >= 2);
    const int  p = s & 1;
    const unsigned T0 = (s>>1)&3;
    const unsigned w32_0 = ((T0&1)?0x4000u:0u) | ((T0&2)?0x40000000u:0u);
    const u64 tg0 = ((u64)w32_0<<32)|w32_0;
    const unsigned T1 = ((s-1)>>1)&3;
    const unsigned w32_1 = ((T1&1)?0x4000u:0u) | ((T1&2)?0x40000000u:0u);
    const u64 tg1 = ((u64)w32_1<<32)|w32_1;

    short* ax   = AX[p];   short* ah0   = AH0[p];
    short* ax_n = AX[p^1]; short* ah0_n = AH0[p^1];
    u64* rb0 = ring + (u64)(p*32+g)*2048;
    u64* rb1 = ring + (u64)(((s-1)&1)*32+g)*2048;
    u64* P0a = rb0 + (ka*4+qd)*2;
    u64* P0b = rb0 + (kb*4+qd)*2;
    u64* P0c = rb0 + (kc*4+qd)*2;
    u64* P1a = rb1 + (ka*4+qd)*2 + 1;
    u64* P1b = rb1 + (kb*4+qd)*2 + 1;
    u64* P1c = rb1 + (kc*4+qd)*2 + 1;

    RAW_BAR();  // B0: prev-step LDS writes visible (vmcnt untouched)

    // wave1: flush out(t=s-2) — atomic is oldest in wave1's stream, retires early
    if (doH1x && tid >= 64 && tid < 80){
      int row = tid - 64;
      float v = outacc[p^1][row][0] + outacc[p^1][row][1]
              + outacc[p^1][row][2] + outacc[p^1][row][3];
      if (c == 0) v += bos;
      atomicAdd(&out[(rowbase + row)*TT + (s-2)], v);
    }

    // issue h1(s-2) polls: target published ~0.7P ago -> round-0 hit
    u64 e1a=0, e1b=0, e1c=0;
    if (doH1x){
      asm volatile(
        "global_load_dwordx2 %0, %3, off sc0 sc1\n\t"
        "global_load_dwordx2 %1, %4, off sc0 sc1\n\t"
        "global_load_dwordx2 %2, %5, off sc0 sc1"
        : "=&v"(e1a),"=&v"(e1b),"=&v"(e1c)
        : "v"(P1a),"v"(P1b),"v"(P1c) : "memory");
    }

    // x prefetch via asm, CLAMPED so the vmcnt stream is uniform for all doL0 steps
    float xf = 0.0f;
    if (doL0){
      int sx = (s+1 < TT) ? s+1 : TT-1;
      const float* xp = x + (rowbase+(tid>>4))*TT*DD + sx*DD + (tid&15);
      asm volatile("global_load_dword %0, %1, off" : "=&v"(xf) : "v"(xp) : "memory");
    }

    // ---- L0: 36 MFMA -> epi -> publish h0(s) -> own h0 frags ----
    u64 pv0 = 0;
    if (doL0){
      f32x4 acc0[4];
#pragma unroll
      for (int nt=0; nt<4; ++nt) acc0[nt] = zero;
      {
        short8 a = *(const short8*)(ax + lane*8);
#pragma unroll
        for (int nt=0; nt<4; ++nt)
          acc0[nt] = __builtin_amdgcn_mfma_f32_16x16x32_bf16(a, F0[nt], acc0[nt], 0,0,0);
      }
#pragma unroll
      for (int ks=0; ks<8; ++ks){
        short8 a = *(const short8*)(ah0 + ks*512 + lane*8);
#pragma unroll
        for (int nt=0; nt<4; ++nt)
          acc0[nt] = __builtin_amdgcn_mfma_f32_16x16x32_bf16(a, F0[(ks+1)*4+nt], acc0[nt], 0,0,0);
      }
      float h0v[4];
#pragma unroll
      for (int r=0; r<4; ++r){
        float iv = sigm (acc0[0][r] + bia0[0]);
        float fv = sigm (acc0[1][r] + bia0[1]);
        float gv = tanhx(acc0[2][r] + bia0[2]);
        float ov = sigm (acc0[3][r] + bia0[3]);
        float cc = fv*c0[r] + iv*gv;
        c0[r] = cc;
        h0v[r] = ov * tanhx(cc);
      }
      pv0 = (((u64)cvtpk(h0v[2], h0v[3])) << 32) | cvtpk(h0v[0], h0v[1]);
      pub_store(rb0 + (colg*4+quad)*2, pv0 | tg0);
#pragma unroll
      for (int r=0; r<4; ++r)
        ah0_n[fragAddr(colg, quad*4 + r)] = (short)(pv0 >> (16*r));
    }

    // ---- L1a half-1: Wih1 x h0(s-1), ks 0..3 ----
    f32x4 acc1[4];
#pragma unroll
    for (int nt=0; nt<4; ++nt) acc1[nt] = zero;
    if (doL1){
#pragma unroll
      for (int ks=0; ks<4; ++ks){
        short8 a = *(const short8*)(ah0 + ks*512 + lane*8);
#pragma unroll
        for (int nt=0; nt<4; ++nt)
          acc1[nt] = __builtin_amdgcn_mfma_f32_16x16x32_bf16(a, F1[ks*4+nt], acc1[nt], 0,0,0);
      }
    }

    // ---- issue h0(s) polls @~0.37P: 1.2kcy skew margin, 0.43P check window ----
    u64 e0a=0, e0b=0, e0c=0;
    if (doL0){
      asm volatile(
        "global_load_dwordx2 %0, %3, off sc0 sc1\n\t"
        "global_load_dwordx2 %1, %4, off sc0 sc1\n\t"
        "global_load_dwordx2 %2, %5, off sc0 sc1"
        : "=&v"(e0a),"=&v"(e0b),"=&v"(e0c)
        : "v"(P0a),"v"(P0b),"v"(P0c) : "memory");
    }

    // ---- L1a half-2: ks 4..7 ----
    if (doL1){
#pragma unroll
      for (int ks=4; ks<8; ++ks){
        short8 a = *(const short8*)(ah0 + ks*512 + lane*8);
#pragma unroll
        for (int nt=0; nt<4; ++nt)
          acc1[nt] = __builtin_amdgcn_mfma_f32_16x16x32_bf16(a, F1[ks*4+nt], acc1[nt], 0,0,0);
      }
    }

    // ---- check h1 polls; fill AH1 (partners + own pv1_prev) ----
    if (doH1x){
      __builtin_amdgcn_sched_barrier(0);
      if (doL0) asm volatile("s_waitcnt vmcnt(5)" ::: "memory"); // leaves xf,pubH0,h0p x3
      else      asm volatile("s_waitcnt vmcnt(0)" ::: "memory"); // s==TT
      __builtin_amdgcn_sched_barrier(0);
      u64 w1a=0,w1b=0,w1c=0;
      bool f1a=false,f1b=false,f1c=false;
      CHKW(e1a, w1a, f1a, tg1); CHKW(e1b, w1b, f1b, tg1); CHKW(e1c, w1c, f1c, tg1);
      while (!(f1a & f1b & f1c)){
        u64 t0,t1,t2;
        asm volatile(
          "global_load_dwordx2 %0, %3, off sc0 sc1\n\t"
          "global_load_dwordx2 %1, %4, off sc0 sc1\n\t"
          "global_load_dwordx2 %2, %5, off sc0 sc1\n\t"
          "s_waitcnt vmcnt(0)"
          : "=&v"(t0),"=&v"(t1),"=&v"(t2)
          : "v"(P1a),"v"(P1b),"v"(P1c) : "memory");
        __builtin_amdgcn_sched_barrier(0);
        CHKW(t0, w1a, f1a, tg1); CHKW(t1, w1b, f1b, tg1); CHKW(t2, w1c, f1c, tg1);
      }
      // own h1(s-2) from register; partners from polls
#pragma unroll
      for (int r=0; r<4; ++r)
        AH1[fragAddr(colg, quad*4 + r)] = (short)(pv1_prev >> (16*r));
      {
        short* sv = (short*)&w1a;
#pragma unroll
        for (int r=0; r<4; ++r) AH1[fragAddr(ka, qd*4 + r)] = sv[r];
        sv = (short*)&w1b;
#pragma unroll
        for (int r=0; r<4; ++r) AH1[fragAddr(kb, qd*4 + r)] = sv[r];
        sv = (short*)&w1c;
#pragma unroll
        for (int r=0; r<4; ++r) AH1[fragAddr(kc, qd*4 + r)] = sv[r];
      }
    }

    RAW_BAR();  // B1: AH1 ready (h0 polls + pub stores stay in flight)

    // ---- L1b: Whh1 x h1(s-2) -> epi -> publish h1(s-1) -> reduce ----
    u64 pv1 = 0;
    if (doL1){
#pragma unroll
      for (int ks=0; ks<8; ++ks){
        short8 a = *(const short8*)(AH1 + ks*512 + lane*8);
#pragma unroll
        for (int nt=0; nt<4; ++nt)
          acc1[nt] = __builtin_amdgcn_mfma_f32_16x16x32_bf16(a, F1[32+ks*4+nt], acc1[nt], 0,0,0);
      }
      float pr[4], h1v[4];
#pragma unroll
      for (int r=0; r<4; ++r){
        float iv = sigm (acc1[0][r] + bia1[0]);
        float fv = sigm (acc1[1][r] + bia1[1]);
        float gv = tanhx(acc1[2][r] + bia1[2]);
        float ov = sigm (acc1[3][r] + bia1[3]);
        float cc = fv*c1[r] + iv*gv;
        c1[r] = cc;
        float h = ov * tanhx(cc);
        h1v[r] = h;
        pr[r] = h * wo;
      }
      pv1 = (((u64)cvtpk(h1v[2], h1v[3])) << 32) | cvtpk(h1v[0], h1v[1]);
      if (doL0)
        pub_store(rb0 + (colg*4+quad)*2 + 1, pv1 | tg0);
#pragma unroll
      for (int m=1; m<16; m<<=1){
#pragma unroll
        for (int r=0; r<4; ++r) pr[r] += __shfl_xor(pr[r], m, 64);
      }
      if (col16 == 0){
#pragma unroll
        for (int r=0; r<4; ++r) outacc[p][quad*4 + r][w] = pr[r];
      }
    }

    // ---- tail: AX stage (vmcnt(4) covers xf) -> h0 check (vmcnt(1)) -> frags ----
    if (doL0){
      __builtin_amdgcn_sched_barrier(0);
      asm volatile("s_waitcnt vmcnt(4)" ::: "memory");   // xf retired; h0p x3 + pubH1 out
      __builtin_amdgcn_sched_barrier(0);
      if (s+1 < TT)
        ax_n[fragAddr(tid & 15, tid >> 4)] = f2bf(xf);

      if (doL1) asm volatile("s_waitcnt vmcnt(1)" ::: "memory");  // leaves pubH1
      else      asm volatile("s_waitcnt vmcnt(0)" ::: "memory");  // s==0
      __builtin_amdgcn_sched_barrier(0);
      u64 w0a=0,w0b=0,w0c=0;
      bool f0a=false,f0b=false,f0c=false;
      CHKW(e0a, w0a, f0a, tg0); CHKW(e0b, w0b, f0b, tg0); CHKW(e0c, w0c, f0c, tg0);
      while (!(f0a & f0b & f0c)){
        u64 t0,t1,t2;
        asm volatile(
          "global_load_dwordx2 %0, %3, off sc0 sc1\n\t"
          "global_load_dwordx2 %1, %4, off sc0 sc1\n\t"
          "global_load_dwordx2 %2, %5, off sc0 sc1\n\t"
          "s_waitcnt vmcnt(0)"
          : "=&v"(t0),"=&v"(t1),"=&v"(t2)
          : "v"(P0a),"v"(P0b),"v"(P0c) : "memory");
        __builtin_amdgcn_sched_barrier(0);
        CHKW(t0, w0a, f0a, tg0); CHKW(t1, w0b, f0b, tg0); CHKW(t2, w0c, f0c, tg0);
      }
      {
        short* sv = (short*)&w0a;
#pragma unroll
        for (int r=0; r<4; ++r) ah0_n[fragAddr(ka, qd*4 + r)] = sv[r];
        sv = (short*)&w0b;
#pragma unroll
        for (int r=0; r<4; ++r) ah0_n[fragAddr(kb, qd*4 + r)] = sv[r];
        sv = (short*)&w0c;
#pragma unroll
        for (int r=0; r<4; ++r) ah0_n[fragAddr(kc, qd*4 + r)] = sv[r];
      }
    }

    pv1_prev = pv1;
  }
#undef CHKW

  // ---- final flush: t = TT-1 lives in outacc[TT&1] ----
  RAW_BAR();
  if (tid < 16){
    const int pf = TT & 1;
    float v = outacc[pf][tid][0] + outacc[pf][tid][1]
            + outacc[pf][tid][2] + outacc[pf][tid][3];
    if (c == 0) v += bos;
    atomicAdd(&out[(rowbase + tid)*TT + (TT-1)], v);
  }
}

// ---------------- launch ----------------
extern "C" void kernel_launch(void* const* d_in, const int* in_sizes, int n_in,
                              void* d_out, int out_size, void* d_ws, size_t ws_size,
                              hipStream_t stream)
{
  const float* x    = (const float*)d_in[0];
  const float* xs   = (const float*)d_in[1];
  const float* Wih0 = (const float*)d_in[2];
  const float* Whh0 = (const float*)d_in[3];
  const float* bih0 = (const float*)d_in[4];
  const float* bhh0 = (const float*)d_in[5];
  const float* Wih1 = (const float*)d_in[6];
  const float* Whh1 = (const float*)d_in[7];
  const float* bih1 = (const float*)d_in[8];
  const float* bhh1 = (const float*)d_in[9];
  const float* Ws   = (const float*)d_in[10];
  const float* bs   = (const float*)d_in[11];
  const float* Wo   = (const float*)d_in[12];
  const float* bo   = (const float*)d_in[13];
  float* out = (float*)d_out;

  char* ws = (char*)d_ws;
  short*    Wb0   = (short*)(ws);                // 589824
  short*    Wb1   = (short*)(ws + 589824);       // 1048576 -> 1638400
  float*    h0i   = (float*)(ws + 1638400);      // 524288  -> 2162688
  float*    b0cp  = (float*)(ws + 2162688);      // 4096    -> 2166784
  float*    b1cp  = (float*)(ws + 2166784);      // 4096    -> 2170880
  u64*      ring  = (u64*)(ws + 2170880);        // 1048576 -> 3219456 (~3.22 MB)

  int nswz = 16*36*512 + 16*64*512;
  hipLaunchKernelGGL(prep_weights, dim3((nswz+255)/256), dim3(256), 0, stream,
                     Wih0, Whh0, Wih1, Whh1, Wb0, Wb1);
  hipLaunchKernelGGL(prep_h0, dim3(512), dim3(256), 0, stream, xs, Ws, bs, h0i);
  hipLaunchKernelGGL(prep_bias, dim3(8), dim3(256), 0, stream, bih0, bhh0, bih1, bhh1, b0cp, b1cp);
  hipLaunchKernelGGL(prep_zero, dim3(1024), dim3(256), 0, stream, out, ring);

  hipLaunchKernelGGL(lstm_fused, dim3(128), dim3(256), 0, stream,
                     Wb0, Wb1, h0i, b0cp, b1cp, x, Wo, bo, ring, out);
}